// Round 8
// baseline (1023.990 us; speedup 1.0000x reference)
//
#include <hip/hip_runtime.h>

// Graph-transformer layer, MI355X. N nodes, E edges, H=128, 4 heads x d=32.
// R8: gather -> scatter conversion. k_sortE streams h_E (coalesced read),
// writes bf16 rows PRE-SWIZZLED to sorted positions (fire-and-forget scatter,
// no latency chain). k_edge_s then reads hEs sequentially (16KB/tile), with
// named-reg 1-ahead prefetch of YK/YV and 2-ahead edata. Fallback to R7's
// gather kernel if ws_size is too small for hEs (~290MB total).

typedef __bf16 bf16x8 __attribute__((ext_vector_type(8)));
typedef float f32x4 __attribute__((ext_vector_type(4)));
typedef unsigned short u16x8 __attribute__((ext_vector_type(8)));

#define DEV static __device__ __forceinline__
#define ET 64   // edges per k_edge tile

DEV unsigned short f2b(float f){
  union { float f; unsigned u; } v; v.f = f;
  unsigned r = (v.u + 0x7FFFu + ((v.u >> 16) & 1u)) >> 16;   // RNE
  return (unsigned short)r;
}
DEV float b2f(unsigned short h){
  union { unsigned u; float f; } v; v.u = ((unsigned)h) << 16; return v.f;
}
DEV f32x4 mfma16(bf16x8 a, bf16x8 b, f32x4 c){
  return __builtin_amdgcn_mfma_f32_16x16x32_bf16(a, b, c, 0, 0, 0);
}
DEV u16x8 pack8(float4 a, float4 b){
  u16x8 p;
  p[0]=f2b(a.x); p[1]=f2b(a.y); p[2]=f2b(a.z); p[3]=f2b(a.w);
  p[4]=f2b(b.x); p[5]=f2b(b.y); p[6]=f2b(b.z); p[7]=f2b(b.w);
  return p;
}
DEV float sspf(float x){  // shifted softplus
  return fmaxf(x, 0.f) + log1pf(expf(-fabsf(x))) - 0.69314718055994531f;
}
DEV int idx64probe(const int* __restrict__ ei){
  return (ei[1] | ei[3] | ei[5] | ei[7] | ei[9]) == 0;
}
DEV int ld_row(const int* __restrict__ ei, long eg, long E, int is64, int N){
  int v = is64 ? ei[2*eg] : ei[eg];
  return min(max(v, 0), N - 1);
}
DEV int ld_col(const int* __restrict__ ei, long eg, long E, int is64, int N){
  int v = is64 ? ei[2*(E + eg)] : ei[E + eg];
  return min(max(v, 0), N - 1);
}
DEV unsigned swz(unsigned byteoff, unsigned row){
  return byteoff ^ ((row & 7u) << 4);
}
// raw barrier: drain LDS only; global loads stay in flight (counted vmcnt)
DEV void bar_lds(){
  __builtin_amdgcn_sched_barrier(0);
  asm volatile("s_waitcnt lgkmcnt(0)" ::: "memory");
  __builtin_amdgcn_s_barrier();
  __builtin_amdgcn_sched_barrier(0);
}

// ---- 128x128 MFMA tile helper (nodeprep / post): A in LDS (swizzled) ----
DEV void mma128(const unsigned short* At, const unsigned short* __restrict__ WT,
                int t, f32x4 (&acc)[4][4]){
  const int l = t & 63;
  const int wm = (t >> 7) & 1, wn = (t >> 6) & 1;
#pragma unroll
  for (int m = 0; m < 4; ++m)
#pragma unroll
    for (int n = 0; n < 4; ++n)
      acc[m][n] = f32x4{0.f, 0.f, 0.f, 0.f};
#pragma unroll
  for (int kk = 0; kk < 4; ++kk){
    bf16x8 a[4], b[4];
#pragma unroll
    for (int m = 0; m < 4; ++m){
      int row = wm*64 + m*16 + (l & 15);
      a[m] = *(const bf16x8*)((const char*)At +
              swz((unsigned)(row*256 + kk*64 + ((l >> 4) & 3)*16), (unsigned)row));
    }
#pragma unroll
    for (int n = 0; n < 4; ++n){
      int col = wn*64 + n*16 + (l & 15);
      b[n] = *(const bf16x8*)(WT + col*128 + kk*32 + ((l >> 4) & 3)*8);
    }
#pragma unroll
    for (int m = 0; m < 4; ++m)
#pragma unroll
      for (int n = 0; n < 4; ++n)
        acc[m][n] = mfma16(a[m], b[n], acc[m][n]);
  }
}

// ---- 64x128 MFMA (edge tiles): 4 waves 2m x 2n, wave = 32 rows x 64 cols ----
DEV void mma64(const unsigned short* Ab, const unsigned short* __restrict__ WT,
               int t, f32x4 (&acc)[2][4]){
  const int l = t & 63, wid = t >> 6, wm = wid >> 1, wn = wid & 1;
#pragma unroll
  for (int m = 0; m < 2; ++m)
#pragma unroll
    for (int n = 0; n < 4; ++n) acc[m][n] = f32x4{0.f, 0.f, 0.f, 0.f};
#pragma unroll
  for (int kk = 0; kk < 4; ++kk){
    bf16x8 a[2], b[4];
#pragma unroll
    for (int m = 0; m < 2; ++m){
      int row = wm*32 + m*16 + (l & 15);
      a[m] = *(const bf16x8*)((const char*)Ab +
          swz((unsigned)(row*256 + kk*64 + ((l >> 4) & 3)*16), (unsigned)row));
    }
#pragma unroll
    for (int n = 0; n < 4; ++n){
      int col = wn*64 + n*16 + (l & 15);
      b[n] = *(const bf16x8*)(WT + col*128 + kk*32 + ((l >> 4) & 3)*8);
    }
#pragma unroll
    for (int m = 0; m < 2; ++m)
#pragma unroll
      for (int n = 0; n < 4; ++n)
        acc[m][n] = mfma16(a[m], b[n], acc[m][n]);
  }
}
DEV void store_acc64(unsigned short* Kt, const f32x4 (&acc)[2][4], int t){
  const int l = t & 63, wid = t >> 6, wm = wid >> 1, wn = wid & 1;
#pragma unroll
  for (int m = 0; m < 2; ++m)
#pragma unroll
    for (int n = 0; n < 4; ++n)
#pragma unroll
      for (int reg = 0; reg < 4; ++reg){
        int er = wm*32 + m*16 + ((l >> 4) & 3)*4 + reg;
        int col = wn*64 + n*16 + (l & 15);
        *(unsigned short*)((char*)Kt + swz((unsigned)(er*256 + col*2), (unsigned)er))
            = f2b(acc[m][n][reg]);
      }
}

__global__ void k_zero(float4* __restrict__ p, long n){
  long i = (long)blockIdx.x * blockDim.x + threadIdx.x;
  const long st = (long)gridDim.x * blockDim.x;
  const float4 z = {0.f, 0.f, 0.f, 0.f};
  for (; i < n; i += st) p[i] = z;
}

// ---- weight prep: fp32 [k][n] -> bf16 [n][k] blobs ----
__global__ void k_wprep(const float* __restrict__ WQ, const float* __restrict__ WK,
                        const float* __restrict__ WV, const float* __restrict__ WO,
                        const float* __restrict__ Wi, const float* __restrict__ Wo2,
                        unsigned short* WQT, unsigned short* WKtT, unsigned short* WKbT,
                        unsigned short* WVtT, unsigned short* WVbT, unsigned short* WOT,
                        unsigned short* WinT, unsigned short* WouT){
  int id = blockIdx.x * 256 + threadIdx.x;
  int n = id >> 7, k = id & 127;
  int d = n * 128 + k;
  WQT[d]  = f2b(WQ[k*128 + n]);
  WKtT[d] = f2b(WK[k*128 + n]);
  WKbT[d] = f2b(WK[(k+128)*128 + n]);
  WVtT[d] = f2b(WV[k*128 + n]);
  WVbT[d] = f2b(WV[(k+128)*128 + n]);
  WOT[d]  = f2b(WO[k*128 + n]);
  WinT[d] = f2b(Wi[k*128 + n]);
  WouT[d] = f2b(Wo2[k*128 + n]);
}

// ---- counting sort by destination row ----
__global__ void k_hist(const int* __restrict__ ei, int* __restrict__ cnt, long E, int N){
  const int is64 = idx64probe(ei);
  long i = (long)blockIdx.x * blockDim.x + threadIdx.x;
  const long st = (long)gridDim.x * blockDim.x;
  for (; i < E; i += st) atomicAdd(&cnt[ld_row(ei, i, E, is64, N)], 1);
}

DEV int wave_incl_scan(int v, int lane){
#pragma unroll
  for (int ofs = 1; ofs < 64; ofs <<= 1){
    int u = __shfl_up(v, ofs, 64);
    if (lane >= ofs) v += u;
  }
  return v;
}

// chunked exclusive scan: cnt -> cursor; edata sentinels; hEs tail zero
__global__ __launch_bounds__(1024) void k_scan(const int* __restrict__ cnt,
                                               int* __restrict__ cursor,
                                               int4* __restrict__ edata,
                                               unsigned short* hEs,
                                               long E, long NT, int N){
  __shared__ int wsum[16], woff[16];
  const int t = threadIdx.x, lane = t & 63, w = t >> 6;
  const int C = (N + 1023) / 1024;
  const int base = t * C;
  int s = 0;
  for (int j = 0; j < C; ++j) if (base + j < N) s += cnt[base + j];
  int incl = wave_incl_scan(s, lane);
  if (lane == 63) wsum[w] = incl;
  __syncthreads();
  if (t == 0){
    int run = 0;
#pragma unroll
    for (int i = 0; i < 16; ++i){ woff[i] = run; run += wsum[i]; }
  }
  __syncthreads();
  int run = woff[w] + incl - s;
  for (int j = 0; j < C; ++j)
    if (base + j < N){ cursor[base + j] = run; run += cnt[base + j]; }
  // edata sentinels: [0] and [E+1 .. E+66] get row = -2
  if (t < 67){
    long gi = (t == 0) ? 0 : (E + t);
    edata[gi] = make_int4(0, -2, 0, 0);
  }
  // hEs tail rows [E, NT*ET) -> zero (<=16KB)
  if (hEs){
    long tailB = (NT*ET - E) * 256;
    if ((long)t * 16 < tailB){
      u16x8 z = {0,0,0,0,0,0,0,0};
      *(u16x8*)((char*)hEs + E*256 + (long)t*16) = z;
    }
  }
}

__global__ void k_scatter(const int* __restrict__ ei, int* __restrict__ cursor,
                          int4* __restrict__ edata, int* __restrict__ invpos,
                          long E, int N){
  const int is64 = idx64probe(ei);
  long i = (long)blockIdx.x * blockDim.x + threadIdx.x;
  const long st = (long)gridDim.x * blockDim.x;
  for (; i < E; i += st){
    int r = ld_row(ei, i, E, is64, N);
    int c = ld_col(ei, i, E, is64, N);
    int pos = atomicAdd(&cursor[r], 1);
    edata[1 + (long)pos] = make_int4((int)i, r, c, 0);
    invpos[i] = pos;
  }
}

// ---- stream h_E (orig order) -> bf16, pre-swizzled, sorted positions ----
__global__ __launch_bounds__(256) void k_sortE(
    const float* __restrict__ hE, const int* __restrict__ invpos,
    unsigned short* __restrict__ hEs, long E){
  const int s = threadIdx.x & 7;         // 16-float slice
  const int eo = threadIdx.x >> 3;       // 0..31
  const long stride = (long)gridDim.x * 32;
  for (long e = (long)blockIdx.x * 32 + eo; e < E; e += stride){
    const float4* src = (const float4*)(hE + e*128 + s*16);
    float4 f0 = src[0], f1 = src[1], f2 = src[2], f3 = src[3];
    long pos = invpos[e];
    unsigned x = ((unsigned)(pos & 7)) << 4;
    char* dst = (char*)hEs + pos*256;
    *(u16x8*)(dst + (((unsigned)(s*32))      ^ x)) = pack8(f0, f1);
    *(u16x8*)(dst + (((unsigned)(s*32 + 16)) ^ x)) = pack8(f2, f3);
  }
}

// ---- node prep: LN1(h_V) -> y ; Q=y@WQ ; YKV interleaved = {y@WKb, y@WVb} ----
__global__ __launch_bounds__(256) void k_nodeprep(
    const float* __restrict__ hV, const float* __restrict__ l1s, const float* __restrict__ l1b,
    const unsigned short* __restrict__ WQT, const unsigned short* __restrict__ WKbT,
    const unsigned short* __restrict__ WVbT,
    unsigned short* __restrict__ Qbf, unsigned short* __restrict__ YKVbf, int N){
  __shared__ unsigned short At[128*128];
  __shared__ float ps[256], pss[256];
  __shared__ float scs[128], bis[128];
  const int t = threadIdx.x;
  if (t < 128){ scs[t] = l1s[t]; bis[t] = l1b[t]; }
  const int r0 = blockIdx.x * 128;
  const int rl = t & 127, hf = t >> 7;
  const int r = r0 + rl;
  const float4* xp = (const float4*)(hV + (size_t)r*128 + hf*64);
  float s = 0.f, ss = 0.f;
  if (r < N){
#pragma unroll
    for (int i = 0; i < 16; ++i){
      float4 v = xp[i];
      s  += (v.x + v.y) + (v.z + v.w);
      ss += (v.x*v.x + v.y*v.y) + (v.z*v.z + v.w*v.w);
    }
  }
  ps[t] = s; pss[t] = ss;
  __syncthreads();
  const float mu  = (ps[t] + ps[t ^ 128]) * 0.0078125f;
  const float var = (pss[t] + pss[t ^ 128]) * 0.0078125f - mu*mu;
  const float rs  = rsqrtf(var + 1e-5f);
#pragma unroll
  for (int i = 0; i < 8; ++i){
    const int c = hf*64 + i*8;
    u16x8 p = {0,0,0,0,0,0,0,0};
    if (r < N){
      float4 v0 = xp[2*i], v1 = xp[2*i+1];
      p[0] = f2b((v0.x - mu)*rs*scs[c+0] + bis[c+0]);
      p[1] = f2b((v0.y - mu)*rs*scs[c+1] + bis[c+1]);
      p[2] = f2b((v0.z - mu)*rs*scs[c+2] + bis[c+2]);
      p[3] = f2b((v0.w - mu)*rs*scs[c+3] + bis[c+3]);
      p[4] = f2b((v1.x - mu)*rs*scs[c+4] + bis[c+4]);
      p[5] = f2b((v1.y - mu)*rs*scs[c+5] + bis[c+5]);
      p[6] = f2b((v1.z - mu)*rs*scs[c+6] + bis[c+6]);
      p[7] = f2b((v1.w - mu)*rs*scs[c+7] + bis[c+7]);
    }
    *(u16x8*)((char*)At + swz((unsigned)(rl*256 + c*2), (unsigned)rl)) = p;
  }
  __syncthreads();
  const int l = t & 63, wm = (t >> 7) & 1, wn = (t >> 6) & 1;
  f32x4 acc[4][4];
  for (int g = 0; g < 3; ++g){
    const unsigned short* WT = (g == 0) ? WQT : (g == 1) ? WKbT : WVbT;
    mma128(At, WT, t, acc);
#pragma unroll
    for (int m = 0; m < 4; ++m)
#pragma unroll
      for (int reg = 0; reg < 4; ++reg){
        int row = wm*64 + m*16 + ((l >> 4) & 3)*4 + reg;
        int gr = r0 + row;
        if (gr < N){
#pragma unroll
          for (int n = 0; n < 4; ++n){
            int col = wn*64 + n*16 + (l & 15);
            unsigned short v = f2b(acc[m][n][reg]);
            if (g == 0)      Qbf[(size_t)gr*128 + col] = v;
            else if (g == 1) YKVbf[(size_t)gr*256 + col] = v;
            else             YKVbf[(size_t)gr*256 + 128 + col] = v;
          }
        }
      }
  }
}

// ---- STREAM edge pass: sequential hEs tiles, named-reg prefetch ----
__global__ __launch_bounds__(256, 3) void k_edge_s(
    const unsigned short* __restrict__ hEs,
    const unsigned short* __restrict__ WKtT, const unsigned short* __restrict__ WVtT,
    const unsigned short* __restrict__ Qbf, const unsigned short* __restrict__ YKVbf,
    const int4* __restrict__ edata,
    float* __restrict__ num, float* __restrict__ den,
    long E, long NT){
  __shared__ unsigned short Ab[ET*128];
  __shared__ unsigned short Kt[ET*128];
  __shared__ float aS[ET][4];
  __shared__ int rowsT[2][ET + 2];

  const int t = threadIdx.x;
  const int er = t >> 2, q = t & 3;     // 4 threads per edge; q = head / 64B slice
  const long b0 = blockIdx.x, G = gridDim.x;
  const long ntloc = (b0 < NT) ? ((NT - 1 - b0) / G + 1) : 0;
  if (ntloc == 0) return;
  auto tileof = [&](long i) -> long {
    long tt = b0 + i * G; return (tt < NT) ? tt : (NT - 1);
  };

  // prologue: tile0 fully staged; tile1 meta staged
  int4 edA = edata[1 + tileof(0)*ET + er];
  int4 edB = edata[1 + tileof(1)*ET + er];
  int sA0 = edata[tileof(0)*ET].y,  sA1 = edata[1 + tileof(0)*ET + ET].y;
  int sB0 = edata[tileof(1)*ET].y,  sB1 = edata[1 + tileof(1)*ET + ET].y;
  u16x8 g0, g1, g2, g3, yk0, yk1, yk2, yk3, yv0, yv1, yv2, yv3;
  {
    const char* hp = (const char*)hEs + (size_t)tileof(0)*ET*256 + er*256 + q*64;
    g0 = *(const u16x8*)(hp);      g1 = *(const u16x8*)(hp + 16);
    g2 = *(const u16x8*)(hp + 32); g3 = *(const u16x8*)(hp + 48);
    const char* kp = (const char*)YKVbf + (size_t)max(edA.z, 0)*512 + q*64;
    yk0 = *(const u16x8*)(kp);      yk1 = *(const u16x8*)(kp + 16);
    yk2 = *(const u16x8*)(kp + 32); yk3 = *(const u16x8*)(kp + 48);
    const char* vp = kp + 256;
    yv0 = *(const u16x8*)(vp);      yv1 = *(const u16x8*)(vp + 16);
    yv2 = *(const u16x8*)(vp + 32); yv3 = *(const u16x8*)(vp + 48);
  }

  for (long it = 0; it < ntloc; ++it){
    const int par = (int)(it & 1);
    // phase 0: meta -> LDS; staged hEs regs -> Ab (raw copy, pre-swizzled);
    //          rotate ahead-regs; issue edata(t+2) + hEs(t+1)
    if (q == 0) rowsT[par][1 + er] = edA.y;
    if (t == 0){ rowsT[par][0] = sA0; rowsT[par][1 + ET] = sA1; }
    {
      char* ab = (char*)Ab + er*256 + q*64;
      *(u16x8*)(ab)      = g0; *(u16x8*)(ab + 16) = g1;
      *(u16x8*)(ab + 32) = g2; *(u16x8*)(ab + 48) = g3;
    }
    edA = edB; sA0 = sB0; sA1 = sB1;
    edB = edata[1 + tileof(it + 2)*ET + er];
    sB0 = edata[tileof(it + 2)*ET].y;
    sB1 = edata[1 + tileof(it + 2)*ET + ET].y;
    {
      const char* hp = (const char*)hEs + (size_t)tileof(it + 1)*ET*256 + er*256 + q*64;
      g0 = *(const u16x8*)(hp);      g1 = *(const u16x8*)(hp + 16);
      g2 = *(const u16x8*)(hp + 32); g3 = *(const u16x8*)(hp + 48);
    }
    bar_lds();
    // phase 1: K = hE_tile @ WKtop
    { f32x4 acc[2][4]; mma64(Ab, WKtT, t, acc); store_acc64(Kt, acc, t); }
    bar_lds();
    // phase 2: logits (thread = edge er, head q): Q[row].(K + YK)
    {
      const int r = rowsT[par][1 + er];
      const int ra = max(r, 0);
      const char* qp = (const char*)Qbf + (size_t)ra*256 + q*64;
      u16x8 q0 = *(const u16x8*)(qp),      q1 = *(const u16x8*)(qp + 16),
            q2 = *(const u16x8*)(qp + 32), q3 = *(const u16x8*)(qp + 48);
      const unsigned xb = ((unsigned)(er & 7)) << 4;
      const char* kb = (const char*)Kt;
      u16x8 c0 = *(const u16x8*)(kb + (((unsigned)(er*256 + q*64))      ^ xb));
      u16x8 c1 = *(const u16x8*)(kb + (((unsigned)(er*256 + q*64 + 16)) ^ xb));
      u16x8 c2 = *(const u16x8*)(kb + (((unsigned)(er*256 + q*64 + 32)) ^ xb));
      u16x8 c3 = *(const u16x8*)(kb + (((unsigned)(er*256 + q*64 + 48)) ^ xb));
      float pl = 0.f;
#pragma unroll
      for (int j = 0; j < 8; ++j){
        pl += b2f(q0[j]) * (b2f(c0[j]) + b2f(yk0[j]));
        pl += b2f(q1[j]) * (b2f(c1[j]) + b2f(yk1[j]));
        pl += b2f(q2[j]) * (b2f(c2[j]) + b2f(yk2[j]));
        pl += b2f(q3[j]) * (b2f(c3[j]) + b2f(yk3[j]));
      }
      aS[er][q] = (r >= 0) ? expf(pl) : 0.f;
    }
    bar_lds();
    // phase 3: V = hE_tile @ WVtop (overwrites Kt)
    { f32x4 acc[2][4]; mma64(Ab, WVtT, t, acc); store_acc64(Kt, acc, t); }
    bar_lds();
    // phase 4: V += staged YV; then issue YK/YV for t+1 (edA = rec(t+1))
    {
      const unsigned xb = ((unsigned)(er & 7)) << 4;
      char* kb = (char*)Kt;
      u16x8* p0 = (u16x8*)(kb + (((unsigned)(er*256 + q*64))      ^ xb));
      u16x8* p1 = (u16x8*)(kb + (((unsigned)(er*256 + q*64 + 16)) ^ xb));
      u16x8* p2 = (u16x8*)(kb + (((unsigned)(er*256 + q*64 + 32)) ^ xb));
      u16x8* p3 = (u16x8*)(kb + (((unsigned)(er*256 + q*64 + 48)) ^ xb));
      u16x8 a0 = *p0, a1 = *p1, a2 = *p2, a3 = *p3, o0, o1, o2, o3;
#pragma unroll
      for (int j = 0; j < 8; ++j){
        o0[j] = f2b(b2f(a0[j]) + b2f(yv0[j]));
        o1[j] = f2b(b2f(a1[j]) + b2f(yv1[j]));
        o2[j] = f2b(b2f(a2[j]) + b2f(yv2[j]));
        o3[j] = f2b(b2f(a3[j]) + b2f(yv3[j]));
      }
      *p0 = o0; *p1 = o1; *p2 = o2; *p3 = o3;
    }
    {
      const char* kp = (const char*)YKVbf + (size_t)max(edA.z, 0)*512 + q*64;
      yk0 = *(const u16x8*)(kp);      yk1 = *(const u16x8*)(kp + 16);
      yk2 = *(const u16x8*)(kp + 32); yk3 = *(const u16x8*)(kp + 48);
      const char* vp = kp + 256;
      yv0 = *(const u16x8*)(vp);      yv1 = *(const u16x8*)(vp + 16);
      yv2 = *(const u16x8*)(vp + 32); yv3 = *(const u16x8*)(vp + 48);
    }
    bar_lds();
    // phase 5: walk — segment reduce; plain store iff full segment owned
    {
      const int c = t & 127, half = t >> 7, hh = c >> 5;
      const int eb = half * 32;
      float accv = 0.f, accd = 0.f;
      int cur = rowsT[par][1 + eb], rs = eb;
      for (int e = eb; e < eb + 32; ++e){
        int r = rowsT[par][1 + e];
        if (r != cur){
          if (cur >= 0){
            bool own = (rowsT[par][rs] != cur);
            float* np = num + (size_t)cur*128 + c;
            if (own) *np = accv; else atomicAdd(np, accv);
            if (c < 4){
              float* dp = den + (size_t)cur*4 + c;
              if (own) *dp = accd; else atomicAdd(dp, accd);
            }
          }
          cur = r; rs = e; accv = 0.f; accd = 0.f;
        }
        float a = aS[e][hh];
        accv += a * b2f(*(const unsigned short*)((const char*)Kt +
                  swz((unsigned)(e*256 + c*2), (unsigned)e)));
        if (c < 4) accd += aS[e][c];
      }
      if (cur >= 0){
        bool own = (rowsT[par][rs] != cur) && (rowsT[par][1 + eb + 32] != cur);
        float* np = num + (size_t)cur*128 + c;
        if (own) *np = accv; else atomicAdd(np, accv);
        if (c < 4){
          float* dp = den + (size_t)cur*4 + c;
          if (own) *dp = accd; else atomicAdd(dp, accd);
        }
      }
    }
    // no trailing barrier: phase0(t+1) touches only Ab/rowsT[par^1] (disjoint
    // from walk readers); post-phase0 barrier gates everything else.
  }
}

// ---- GATHER edge pass (R7 fallback, used if ws too small for hEs) ----
__global__ __launch_bounds__(256, 3) void k_edge_g(
    const float* __restrict__ hE,
    const unsigned short* __restrict__ WKtT, const unsigned short* __restrict__ WVtT,
    const unsigned short* __restrict__ Qbf, const unsigned short* __restrict__ YKVbf,
    const int4* __restrict__ edata,
    float* __restrict__ num, float* __restrict__ den,
    long E, long NT){
  __shared__ unsigned short Ab[ET*128];
  __shared__ unsigned short Kt[ET*128];
  __shared__ float aS[ET][4];
  __shared__ int rowsT[2][ET + 2];
  __shared__ int colT[2][ET];

  const int t = threadIdx.x;
  const int rr = t & 63, sl = t >> 6;
  const long b0 = blockIdx.x, G = gridDim.x;
  const long ntloc = (b0 < NT) ? ((NT - 1 - b0) / G + 1) : 0;
  if (ntloc == 0) return;
  auto tileof = [&](long i) -> long {
    long tt = b0 + i * G; return (tt < NT) ? tt : (NT - 1);
  };

  int4 edc = edata[1 + tileof(0)*ET + rr];
  long pe0 = (long)edc.x; pe0 = pe0 < 0 ? 0 : pe0;
  const float4* hp0 = (const float4*)(hE + (size_t)pe0*128 + sl*32);
  float4 h0=hp0[0], h1=hp0[1], h2=hp0[2], h3=hp0[3],
         h4=hp0[4], h5=hp0[5], h6=hp0[6], h7=hp0[7];
  int4 edn = edata[1 + tileof(1)*ET + rr];

  for (long it = 0; it < ntloc; ++it){
    const int par = (int)(it & 1);
    if (t < ET){ rowsT[par][1 + t] = edc.y; colT[par][t] = edc.z; }
    if (t == 64) rowsT[par][0]      = edata[tileof(it)*ET].y;
    if (t == 65) rowsT[par][ET + 1] = edata[1 + tileof(it)*ET + ET].y;
    {
      unsigned base = (unsigned)(rr*256 + sl*64);
      unsigned x = ((unsigned)(rr & 7)) << 4;
      *(u16x8*)((char*)Ab + ((base     ) ^ x)) = pack8(h0, h1);
      *(u16x8*)((char*)Ab + ((base + 16) ^ x)) = pack8(h2, h3);
      *(u16x8*)((char*)Ab + ((base + 32) ^ x)) = pack8(h4, h5);
      *(u16x8*)((char*)Ab + ((base + 48) ^ x)) = pack8(h6, h7);
    }
    edc = edn;
    edn = edata[1 + tileof(it + 2)*ET + rr];
    {
      long pe = (long)edc.x; pe = pe < 0 ? 0 : pe;
      const float4* np = (const float4*)(hE + (size_t)pe*128 + sl*32);
      h0 = np[0]; h1 = np[1]; h2 = np[2]; h3 = np[3];
      h4 = np[4]; h5 = np[5]; h6 = np[6]; h7 = np[7];
    }
    bar_lds();
    { f32x4 acc[2][4]; mma64(Ab, WKtT, t, acc); store_acc64(Kt, acc, t); }
    bar_lds();
    {
      const int e = t >> 2, q = t & 3;
      const int r = rowsT[par][1 + e], c = colT[par][e];
      const int ra = max(r, 0), ca = max(c, 0);
      const u16x8* qp = (const u16x8*)(Qbf  + (size_t)ra*128 + q*32);
      const u16x8* kp = (const u16x8*)(YKVbf + (size_t)ca*256 + q*32);
      const unsigned xb = ((unsigned)(e & 7)) << 4;
      float pl = 0.f;
#pragma unroll
      for (int k = 0; k < 4; ++k){
        u16x8 qv = qp[k], yk = kp[k];
        u16x8 kv = *(const u16x8*)((const char*)Kt +
            (((unsigned)(e*256 + q*64 + k*16)) ^ xb));
#pragma unroll
        for (int j = 0; j < 8; ++j) pl += b2f(qv[j]) * (b2f(kv[j]) + b2f(yk[j]));
      }
      aS[e][q] = (r >= 0) ? expf(pl) : 0.f;
    }
    bar_lds();
    { f32x4 acc[2][4]; mma64(Ab, WVtT, t, acc); store_acc64(Kt, acc, t); }
    bar_lds();
    {
      const int e = t >> 2, q = t & 3;
      const int ca = max(colT[par][e], 0);
      const u16x8* vp = (const u16x8*)(YKVbf + (size_t)ca*256 + 128 + q*32);
      const unsigned xb = ((unsigned)(e & 7)) << 4;
#pragma unroll
      for (int k = 0; k < 4; ++k){
        u16x8* pp = (u16x8*)((char*)Kt + (((unsigned)(e*256 + q*64 + k*16)) ^ xb));
        u16x8 a = *pp, b = vp[k], o;
#pragma unroll
        for (int j = 0; j < 8; ++j) o[j] = f2b(b2f(a[j]) + b2f(b[j]));
        *pp = o;
      }
    }
    bar_lds();
    {
      const int c = t & 127, half = t >> 7, hh = c >> 5;
      const int eb = half * 32;
      float accv = 0.f, accd = 0.f;
      int cur = rowsT[par][1 + eb], rs = eb;
      for (int e = eb; e < eb + 32; ++e){
        int r = rowsT[par][1 + e];
        if (r != cur){
          if (cur >= 0){
            bool own = (rowsT[par][rs] != cur);
            float* np = num + (size_t)cur*128 + c;
            if (own) *np = accv; else atomicAdd(np, accv);
            if (c < 4){
              float* dp = den + (size_t)cur*4 + c;
              if (own) *dp = accd; else atomicAdd(dp, accd);
            }
          }
          cur = r; rs = e; accv = 0.f; accd = 0.f;
        }
        float a = aS[e][hh];
        accv += a * b2f(*(const unsigned short*)((const char*)Kt +
                  swz((unsigned)(e*256 + c*2), (unsigned)e)));
        if (c < 4) accd += aS[e][c];
      }
      if (cur >= 0){
        bool own = (rowsT[par][rs] != cur) && (rowsT[par][1 + eb + 32] != cur);
        float* np = num + (size_t)cur*128 + c;
        if (own) *np = accv; else atomicAdd(np, accv);
        if (c < 4){
          float* dp = den + (size_t)cur*4 + c;
          if (own) *dp = accd; else atomicAdd(dp, accd);
        }
      }
    }
  }
}

// ---- fused post: h1 = hV + ssp(num/den/sqrt d)@WO ; out = h1 + FFN(LN2(h1)) ----
__global__ __launch_bounds__(256, 2) void k_post(
    const float* __restrict__ hV, const float* __restrict__ num,
    const float* __restrict__ den,
    const unsigned short* __restrict__ WOT, const unsigned short* __restrict__ WinT,
    const unsigned short* __restrict__ WouT,
    const float* __restrict__ l2s, const float* __restrict__ l2b,
    const float* __restrict__ bin, const float* __restrict__ bou,
    float* __restrict__ out, int N){
  __shared__ unsigned short At[128*128];
  __shared__ float ps[128][2], pq[128][2];
  __shared__ float scs[128], bis[128], binS[128], bouS[128];
  const int t = threadIdx.x;
  if (t < 128){ scs[t] = l2s[t]; bis[t] = l2b[t]; binS[t] = bin[t]; bouS[t] = bou[t]; }
  const int r0 = blockIdx.x * 128;
  const int rl = t & 127, hf = t >> 7;
  const int r = r0 + rl;
  const float inv = 0.17677669529663687f;  // 1/sqrt(32)
  float i0 = 0.f, i1 = 0.f;
  if (r < N){
    float d0 = den[(size_t)r*4 + 2*hf], d1 = den[(size_t)r*4 + 2*hf + 1];
    i0 = (d0 > 0.f) ? inv / d0 : 0.f;
    i1 = (d1 > 0.f) ? inv / d1 : 0.f;
  }
  const float4* ap = (const float4*)(num + (size_t)r*128 + hf*64);
#pragma unroll
  for (int i = 0; i < 8; ++i){
    u16x8 p = {0,0,0,0,0,0,0,0};
    if (r < N){
      float sc = (i < 4) ? i0 : i1;
      float4 v0 = ap[2*i], v1 = ap[2*i+1];
      p[0]=f2b(sspf(v0.x*sc)); p[1]=f2b(sspf(v0.y*sc)); p[2]=f2b(sspf(v0.z*sc)); p[3]=f2b(sspf(v0.w*sc));
      p[4]=f2b(sspf(v1.x*sc)); p[5]=f2b(sspf(v1.y*sc)); p[6]=f2b(sspf(v1.z*sc)); p[7]=f2b(sspf(v1.w*sc));
    }
    *(u16x8*)((char*)At + swz((unsigned)(rl*256 + hf*128 + i*16), (unsigned)rl)) = p;
  }
  __syncthreads();
  const int l = t & 63, wm = (t >> 7) & 1, wn = (t >> 6) & 1;
  f32x4 acc[4][4];
  mma128(At, WOT, t, acc);
  float h1[4][4][4];
#pragma unroll
  for (int m = 0; m < 4; ++m)
#pragma unroll
    for (int reg = 0; reg < 4; ++reg){
      int er = wm*64 + m*16 + ((l >> 4) & 3)*4 + reg;
      int gr = r0 + er;
#pragma unroll
      for (int n = 0; n < 4; ++n){
        int col = wn*64 + n*16 + (l & 15);
        h1[m][n][reg] = acc[m][n][reg] + ((gr < N) ? hV[(size_t)gr*128 + col] : 0.f);
      }
    }
#pragma unroll
  for (int m = 0; m < 4; ++m)
#pragma unroll
    for (int reg = 0; reg < 4; ++reg){
      float s = 0.f, q = 0.f;
#pragma unroll
      for (int n = 0; n < 4; ++n){ float v = h1[m][n][reg]; s += v; q += v*v; }
#pragma unroll
      for (int o = 1; o < 16; o <<= 1){ s += __shfl_xor(s, o); q += __shfl_xor(q, o); }
      if ((l & 15) == 0){
        int er = wm*64 + m*16 + ((l >> 4) & 3)*4 + reg;
        ps[er][wn] = s; pq[er][wn] = q;
      }
    }
  __syncthreads();
#pragma unroll
  for (int m = 0; m < 4; ++m)
#pragma unroll
    for (int reg = 0; reg < 4; ++reg){
      int er = wm*64 + m*16 + ((l >> 4) & 3)*4 + reg;
      float mu  = (ps[er][0] + ps[er][1]) * 0.0078125f;
      float var = (pq[er][0] + pq[er][1]) * 0.0078125f - mu*mu;
      float rsv = rsqrtf(var + 1e-5f);
#pragma unroll
      for (int n = 0; n < 4; ++n){
        int col = wn*64 + n*16 + (l & 15);
        float yv = (h1[m][n][reg] - mu)*rsv*scs[col] + bis[col];
        *(unsigned short*)((char*)At + swz((unsigned)(er*256 + col*2), (unsigned)er)) = f2b(yv);
      }
    }
  __syncthreads();
  mma128(At, WinT, t, acc);
  __syncthreads();
#pragma unroll
  for (int m = 0; m < 4; ++m)
#pragma unroll
    for (int reg = 0; reg < 4; ++reg){
      int er = wm*64 + m*16 + ((l >> 4) & 3)*4 + reg;
#pragma unroll
      for (int n = 0; n < 4; ++n){
        int col = wn*64 + n*16 + (l & 15);
        float v = acc[m][n][reg] + binS[col];
        *(unsigned short*)((char*)At + swz((unsigned)(er*256 + col*2), (unsigned)er))
            = f2b(fmaxf(v, 0.f));
      }
    }
  __syncthreads();
  mma128(At, WouT, t, acc);
#pragma unroll
  for (int m = 0; m < 4; ++m)
#pragma unroll
    for (int reg = 0; reg < 4; ++reg){
      int er = wm*64 + m*16 + ((l >> 4) & 3)*4 + reg;
      int gr = r0 + er;
      if (gr < N){
#pragma unroll
        for (int n = 0; n < 4; ++n){
          int col = wn*64 + n*16 + (l & 15);
          out[(size_t)gr*128 + col] = acc[m][n][reg] + bouS[col] + h1[m][n][reg];
        }
      }
    }
}

extern "C" void kernel_launch(void* const* d_in, const int* in_sizes, int n_in,
                              void* d_out, int out_size, void* d_ws, size_t ws_size,
                              hipStream_t stream)
{
  const float* hV  = (const float*)d_in[0];
  const float* hE  = (const float*)d_in[1];
  const int*   ei  = (const int*)d_in[2];
  const float* WQ  = (const float*)d_in[3];
  const float* WK  = (const float*)d_in[4];
  const float* WV  = (const float*)d_in[5];
  const float* WO  = (const float*)d_in[6];
  const float* l1s = (const float*)d_in[7];
  const float* l1b = (const float*)d_in[8];
  const float* l2s = (const float*)d_in[9];
  const float* l2b = (const float*)d_in[10];
  const float* Wi  = (const float*)d_in[11];
  const float* bi  = (const float*)d_in[12];
  const float* Wo2 = (const float*)d_in[13];
  const float* bo  = (const float*)d_in[14];
  float* out = (float*)d_out;

  const int  N = in_sizes[0] / 128;
  const long E = (long)in_sizes[1] / 128;
  const long NT = (E + ET - 1) / ET;

  char* ws = (char*)d_ws;
  size_t off = 0;
  auto alloc = [&](size_t b){ size_t o = off; off += (b + 255) & ~(size_t)255; return o; };
  const size_t WB = 128*128*sizeof(unsigned short);
  size_t oWQT = alloc(WB), oWKtT = alloc(WB), oWKbT = alloc(WB);
  size_t oWVtT = alloc(WB), oWVbT = alloc(WB), oWOT = alloc(WB);
  size_t oWinT = alloc(WB), oWouT = alloc(WB);
  size_t oQ    = alloc((size_t)N*128*2);
  size_t oYKV  = alloc((size_t)N*256*2);
  size_t oED   = alloc((size_t)(E + 70)*16);
  size_t oINV  = alloc((size_t)E*4);
  size_t oCUR  = alloc((size_t)N*4);
  size_t oCNT  = alloc((size_t)N*4);        // zeroed region starts here
  size_t oDEN  = alloc((size_t)N*4*4);
  size_t oNUM  = alloc((size_t)N*128*4);
  size_t zero_bytes = (oNUM + (size_t)N*128*4) - oCNT;
  size_t oHES  = alloc((size_t)NT*ET*256);  // bf16 sorted h_E, pre-swizzled
  const bool streamMode = (off <= ws_size);

  unsigned short* WQT  = (unsigned short*)(ws + oWQT);
  unsigned short* WKtT = (unsigned short*)(ws + oWKtT);
  unsigned short* WKbT = (unsigned short*)(ws + oWKbT);
  unsigned short* WVtT = (unsigned short*)(ws + oWVtT);
  unsigned short* WVbT = (unsigned short*)(ws + oWVbT);
  unsigned short* WOT  = (unsigned short*)(ws + oWOT);
  unsigned short* WinT = (unsigned short*)(ws + oWinT);
  unsigned short* WouT = (unsigned short*)(ws + oWouT);
  unsigned short* Qbf  = (unsigned short*)(ws + oQ);
  unsigned short* YKVbf= (unsigned short*)(ws + oYKV);
  int4* edata  = (int4*)(ws + oED);
  int*  invpos = (int*)(ws + oINV);
  int*  cursor = (int*)(ws + oCUR);
  int*  cnt    = (int*)(ws + oCNT);
  float* den   = (float*)(ws + oDEN);
  float* num   = (float*)(ws + oNUM);
  unsigned short* hEs = streamMode ? (unsigned short*)(ws + oHES) : nullptr;

  const int nbN = (N + 127) / 128;
  const int nbe = (int)((E + 255) / 256);
  const int gE  = (int)((NT < 768) ? NT : 768);

  k_zero<<<2048, 256, 0, stream>>>((float4*)(ws + oCNT), (long)(zero_bytes / 16));
  k_wprep<<<64, 256, 0, stream>>>(WQ, WK, WV, WO, Wi, Wo2,
                                  WQT, WKtT, WKbT, WVtT, WVbT, WOT, WinT, WouT);
  k_nodeprep<<<nbN, 256, 0, stream>>>(hV, l1s, l1b, WQT, WKbT, WVbT, Qbf, YKVbf, N);
  k_hist<<<nbe, 256, 0, stream>>>(ei, cnt, E, N);
  k_scan<<<1, 1024, 0, stream>>>(cnt, cursor, edata, hEs, E, NT, N);
  k_scatter<<<nbe, 256, 0, stream>>>(ei, cursor, edata, invpos, E, N);
  if (streamMode){
    k_sortE<<<2048, 256, 0, stream>>>(hE, invpos, hEs, E);
    k_edge_s<<<gE, 256, 0, stream>>>(hEs, WKtT, WVtT, Qbf, YKVbf,
                                     edata, num, den, E, NT);
  } else {
    k_edge_g<<<gE, 256, 0, stream>>>(hE, WKtT, WVtT, Qbf, YKVbf,
                                     edata, num, den, E, NT);
  }
  k_post<<<nbN, 256, 0, stream>>>(hV, num, den, WOT, WinT, WouT,
                                  l2s, l2b, bi, bo, out, N);
}